// Round 3
// baseline (90.380 us; speedup 1.0000x reference)
//
#include <hip/hip_runtime.h>
#include <float.h>

// ChamferLoss: B=4, N=16384 src, M=4096 verts, fp32. Single fused kernel.
//
// d2 = p2 + v2 - 2*dot(p,v); p2 folded out of the inner loop (constant per
// point; clamp commutes with min). Verts pre-transformed to {-2x,-2y,-2z,v2}
// -> 3 FMA + 1 min per pair. VALU floor: 268M pairs * 4 lane-ops / 78.6 T/s
// = 13.7 us.
//
// Each block: 128 points, ALL 4096 verts of its batch staged once in LDS
// (exactly 64 KB). Threads = 16 vert-splits (q) x 16 point-groups (g) x 8
// points. LDS layout interleaved lv4[j*16+q]: the 4 q-groups per wave read
// disjoint bank quads (bank = 4q mod 32), broadcast within a group ->
// conflict-free, no padding, exactly 65536 B -> 2 blocks/CU.
//
// Finish: per-block sums via device-scope atomics into ws; counter slot
// zero-initialized by atomicCAS from the harness's 0xAA poison; last block
// sums 512 slots and writes out. One dispatch total.

constexpr int B = 4, N = 16384, M = 4096;
constexpr int TPB = 256;
constexpr int SPLITS = 16;                 // vert splits per block
constexpr int VC = M / SPLITS;             // 256 verts per split
constexpr int P = 8;                       // points per thread
constexpr int PPB = (TPB / SPLITS) * P;    // 128 points per block
constexpr int NBLK = (B * N) / PPB;        // 512 blocks = 2/CU
constexpr unsigned POISON = 0xAAAAAAAAu;

__global__ __launch_bounds__(TPB, 2) void chamfer_fused(
    const float* __restrict__ src, const float* __restrict__ tv,
    float* __restrict__ out, float* __restrict__ ws)
{
    __shared__ float4 lv[M];               // 65536 B, reused for epilogue
    const int blk = blockIdx.x;
    const int b   = blk >> 7;              // 128 blocks per batch
    const int bb  = blk & 127;
    const int t   = threadIdx.x;
    const int q   = t >> 4;                // vert split 0..15
    const int g   = t & 15;                // point group 0..15

    // Stage all batch verts, transformed to {-2x,-2y,-2z,v2}.
    // Store index i = j*16 + q  (vert v = q*256 + j) so lanes write
    // consecutive float4s (perfect ds_write_b128). Global reads scatter but
    // are L2/L3-hot (48 KB/block) and happen once.
    const float* vsrc = tv + (size_t)b * M * 3;
    for (int k = 0; k < SPLITS; ++k) {
        int i  = t + 256 * k;              // LDS slot
        int v  = ((i & 15) << 8) + (i >> 4);
        float x = vsrc[3 * v + 0];
        float y = vsrc[3 * v + 1];
        float z = vsrc[3 * v + 2];
        lv[i] = make_float4(-2.0f * x, -2.0f * y, -2.0f * z,
                            fmaf(x, x, fmaf(y, y, z * z)));
    }

    // This thread's 8 consecutive points (96 B, 16B-aligned).
    const int p0 = b * N + bb * PPB + g * P;
    const float4* pv4 = (const float4*)(src + (size_t)p0 * 3);
    float4 q0 = pv4[0], q1 = pv4[1], q2 = pv4[2],
           q3 = pv4[3], q4 = pv4[4], q5 = pv4[5];
    float px[P], py[P], pz[P], mn[P];
    px[0]=q0.x; py[0]=q0.y; pz[0]=q0.z;
    px[1]=q0.w; py[1]=q1.x; pz[1]=q1.y;
    px[2]=q1.z; py[2]=q1.w; pz[2]=q2.x;
    px[3]=q2.y; py[3]=q2.z; pz[3]=q2.w;
    px[4]=q3.x; py[4]=q3.y; pz[4]=q3.z;
    px[5]=q3.w; py[5]=q4.x; pz[5]=q4.y;
    px[6]=q4.z; py[6]=q4.w; pz[6]=q5.x;
    px[7]=q5.y; py[7]=q5.z; pz[7]=q5.w;
#pragma unroll
    for (int p = 0; p < P; ++p) mn[p] = FLT_MAX;

    __syncthreads();

    // Main loop: split q covers verts [q*256, (q+1)*256).
#pragma unroll 8
    for (int j = 0; j < VC; ++j) {
        float4 v = lv[(j << 4) + q];
#pragma unroll
        for (int p = 0; p < P; ++p) {
            float d = fmaf(v.x, px[p], fmaf(v.y, py[p], fmaf(v.z, pz[p], v.w)));
            mn[p] = fminf(mn[p], d);
        }
    }

    __syncthreads();                       // all LDS vert reads done

    // part[pt][q] = mn + p2, overlaying lv (8 KB of the 64 KB region).
    float* part = (float*)lv;
#pragma unroll
    for (int p = 0; p < P; ++p) {
        float p2 = fmaf(px[p], px[p], fmaf(py[p], py[p], pz[p] * pz[p]));
        part[(g * P + p) * SPLITS + q] = mn[p] + p2;
    }
    __syncthreads();

    // Threads 0..127: final min over the 16 splits, clamp to 0.
    float r = 0.0f;
    if (t < PPB) {
        const float4* row = (const float4*)(part + t * SPLITS);
        float4 a = row[0], c = row[1], d = row[2], e = row[3];
        float m = fminf(
            fminf(fminf(fminf(a.x, a.y), fminf(a.z, a.w)),
                  fminf(fminf(c.x, c.y), fminf(c.z, c.w))),
            fminf(fminf(fminf(d.x, d.y), fminf(d.z, d.w)),
                  fminf(fminf(e.x, e.y), fminf(e.z, e.w))));
        r = fmaxf(m, 0.0f);
    }
    for (int off = 32; off > 0; off >>= 1)
        r += __shfl_down(r, off, 64);

    float* acc = part + 2048;              // bytes 8192.. (disjoint from rows)
    int*  flag = (int*)(part + 2052);
    if (t == 0)  acc[0] = r;
    if (t == 64) acc[1] = r;
    __syncthreads();

    // Per-block sum -> ws[blk] (atomic, device-coherent); counter dance.
    if (t == 0) {
        float bs = acc[0] + acc[1];
        unsigned* cnt = (unsigned*)(ws + NBLK);
        atomicExch(&ws[blk], bs);
        __threadfence();                   // bs visible before counter ops
        (void)atomicCAS(cnt, POISON, 0u);  // first arrival zeroes poison
        __threadfence();
        unsigned n = atomicAdd(cnt, 1u);
        *flag = (n == NBLK - 1) ? 1 : 0;
    }
    __syncthreads();

    // Last block: wave w sums batch w's 128 block-sums, writes out[w].
    if (*flag) {
        int w = t >> 6, lane = t & 63;
        float s = atomicAdd(&ws[w * 128 + lane], 0.0f)
                + atomicAdd(&ws[w * 128 + 64 + lane], 0.0f);
        for (int off = 32; off > 0; off >>= 1)
            s += __shfl_down(s, off, 64);
        if (lane == 0) out[w] = s * (1.0f / N);
    }
}

extern "C" void kernel_launch(void* const* d_in, const int* in_sizes, int n_in,
                              void* d_out, int out_size, void* d_ws, size_t ws_size,
                              hipStream_t stream) {
    const float* src = (const float*)d_in[0];  // (B, N, 3) fp32
    const float* tv  = (const float*)d_in[1];  // (B, M, 3) fp32
    float* out = (float*)d_out;                // (B,) fp32
    float* ws  = (float*)d_ws;                 // 512 sums + 1 counter

    chamfer_fused<<<NBLK, TPB, 0, stream>>>(src, tv, out, ws);
}